// Round 1
// baseline (189.267 us; speedup 1.0000x reference)
//
#include <hip/hip_runtime.h>
#include <hip/hip_bf16.h>
#include <stdint.h>

#define B_ 8
#define T_ 2048
#define C_ 1024
#define H_ 64
#define M_ (B_*T_)   // 16384 rows

typedef __bf16 bf16x8 __attribute__((ext_vector_type(8)));
typedef float  f32x4  __attribute__((ext_vector_type(4)));

__device__ __forceinline__ unsigned short f32_to_bf16(float f) {
    union { float f; uint32_t u; } c; c.f = f;
    uint32_t u = c.u;
    u += 0x7fffu + ((u >> 16) & 1u);   // round-to-nearest-even
    return (unsigned short)(u >> 16);
}

// ---------------- Kernel 1: prepack weights -> bf16 transposed [192][1024] ----
__global__ void prepack_w(const float* __restrict__ Wq, const float* __restrict__ Wk,
                          const float* __restrict__ Wv, unsigned short* __restrict__ wt) {
    int e = blockIdx.x * 256 + threadIdx.x;       // 192*1024 elements
    if (e >= 192 * 1024) return;
    int n = e >> 10, k = e & 1023;
    const float* W = (n < 64) ? Wq : (n < 128) ? Wk : Wv;
    int col = n & 63;
    wt[e] = f32_to_bf16(W[k * 64 + col]);
}

// ---------------- Kernel 2: QKV projection (bf16 MFMA) ------------------------
// X[16384][1024] fp32 @ W[1024][192] -> q,k,v bf16 [16384][64] each.
// Block: 256 thr = 4 waves, 64 rows; K-chunks of 32.
__global__ __launch_bounds__(256) void qkv_kernel(const float* __restrict__ X,
        const unsigned short* __restrict__ wt,
        unsigned short* __restrict__ qb, unsigned short* __restrict__ kb,
        unsigned short* __restrict__ vb) {
    __shared__ unsigned short Xl[64][40];    // 64 rows x 32 k (+8 pad)
    __shared__ unsigned short Wl[192][40];   // 192 n x 32 k (+8 pad)
    const int tid = threadIdx.x;
    const int wave = tid >> 6, lane = tid & 63;
    const int grp = lane >> 4, l15 = lane & 15;
    const int mb = blockIdx.x * 64;

    f32x4 acc[12];
    for (int i = 0; i < 12; i++) acc[i] = (f32x4){0.f, 0.f, 0.f, 0.f};

    for (int k0 = 0; k0 < 1024; k0 += 32) {
        // stage X tile: 64x32 fp32 -> bf16 (512 float4 chunks)
        for (int i = 0; i < 2; i++) {
            int chunk = tid + 256 * i;
            int row = chunk >> 3;
            int c4 = (chunk & 7) * 4;
            float4 xv = *(const float4*)(X + (size_t)(mb + row) * 1024 + k0 + c4);
            unsigned short* p = &Xl[row][c4];
            p[0] = f32_to_bf16(xv.x); p[1] = f32_to_bf16(xv.y);
            p[2] = f32_to_bf16(xv.z); p[3] = f32_to_bf16(xv.w);
        }
        // stage W tile: 192 x 32 bf16 (768 16B chunks)
        for (int i = 0; i < 3; i++) {
            int chunk = tid + 256 * i;
            int n = chunk >> 2;
            int koff = (chunk & 3) * 8;
            *(uint4*)&Wl[n][koff] = *(const uint4*)(wt + (size_t)n * 1024 + k0 + koff);
        }
        __syncthreads();
        bf16x8 af = *(const bf16x8*)&Xl[wave * 16 + l15][grp * 8];
        for (int nt = 0; nt < 12; nt++) {
            bf16x8 bfr = *(const bf16x8*)&Wl[nt * 16 + l15][grp * 8];
            acc[nt] = __builtin_amdgcn_mfma_f32_16x16x32_bf16(af, bfr, acc[nt], 0, 0, 0);
        }
        __syncthreads();
    }
    // epilogue: D row = grp*4+r, col = nt*16+l15
    int r0 = mb + wave * 16 + grp * 4;
    for (int nt = 0; nt < 12; nt++) {
        int col = nt * 16 + l15;
        unsigned short* dst = (col < 64) ? qb : (col < 128) ? kb : vb;
        int c = col & 63;
        for (int r = 0; r < 4; r++)
            dst[(size_t)(r0 + r) * 64 + c] = f32_to_bf16(acc[nt][r]);
    }
}

// ---------------- Kernel 3: transpose V -> vt[B][64][2048] --------------------
__global__ __launch_bounds__(256) void vtrans_kernel(const unsigned short* __restrict__ vb,
                                                     unsigned short* __restrict__ vt) {
    __shared__ unsigned short tile[64][72];
    const int b = blockIdx.y, t0 = blockIdx.x * 64;
    const int tid = threadIdx.x;
    for (int i = 0; i < 2; i++) {
        int chunk = tid + 256 * i;
        int row = chunk >> 3;
        int c8 = (chunk & 7) * 8;
        *(uint4*)&tile[row][c8] = *(const uint4*)(vb + ((size_t)(b * 2048 + t0 + row)) * 64 + c8);
    }
    __syncthreads();
    for (int i = 0; i < 2; i++) {
        int chunk = tid + 256 * i;
        int d = chunk >> 3;
        int t8 = (chunk & 7) * 8;
        unsigned short tmp[8];
        for (int j = 0; j < 8; j++) tmp[j] = tile[t8 + j][d];
        *(uint4*)(vt + ((size_t)b * 64 + d) * 2048 + t0 + t8) = *(uint4*)tmp;
    }
}

// ---------------- Kernel 4: flash attention (causal, online softmax) ----------
// Block: 256 thr = 4 waves; 64 q rows/block (16 per wave). Key tiles of 64.
__global__ __launch_bounds__(256) void attn_kernel(const unsigned short* __restrict__ qb,
        const unsigned short* __restrict__ kb, const unsigned short* __restrict__ vt,
        float* __restrict__ out) {
    __shared__ unsigned short Kl[64][72];        // [key][dim], pad->2-way max
    __shared__ unsigned short Vl[64][72];        // [dim][key]
    __shared__ unsigned short Pl[4][16][72];     // per-wave [q][key]
    const int tid = threadIdx.x;
    const int wave = tid >> 6, lane = tid & 63;
    const int grp = lane >> 4, l15 = lane & 15;
    const int b = blockIdx.y;
    const int qt = blockIdx.x;
    const int qbase = qt * 64;

    // Q fragments, held in registers for the whole kernel
    const unsigned short* qp = qb + ((size_t)b * 2048 + qbase + wave * 16 + l15) * 64 + grp * 8;
    bf16x8 aq0 = *(const bf16x8*)(qp);
    bf16x8 aq1 = *(const bf16x8*)(qp + 32);

    float m_i[4], l_i[4];
    f32x4 acc[4];
    for (int r = 0; r < 4; r++) { m_i[r] = -1e30f; l_i[r] = 0.f; }
    for (int nt = 0; nt < 4; nt++) acc[nt] = (f32x4){0.f, 0.f, 0.f, 0.f};

    const float scale = 0.03125f;   // C^-0.5 = 1/32

    for (int kt = 0; kt <= qt; kt++) {
        const int kbase = kt * 64;
        // stage K tile [64 keys][64 dims] and Vt tile [64 dims][64 keys]
        for (int i = 0; i < 2; i++) {
            int chunk = tid + 256 * i;
            int row = chunk >> 3;
            int c8 = (chunk & 7) * 8;
            *(uint4*)&Kl[row][c8] = *(const uint4*)(kb + ((size_t)b * 2048 + kbase + row) * 64 + c8);
            *(uint4*)&Vl[row][c8] = *(const uint4*)(vt + ((size_t)b * 64 + row) * 2048 + kbase + c8);
        }
        __syncthreads();

        // S = Q K^T  (4 key-subtiles of 16)
        f32x4 s[4];
        for (int nt = 0; nt < 4; nt++) {
            bf16x8 bk0 = *(const bf16x8*)&Kl[nt * 16 + l15][grp * 8];
            bf16x8 bk1 = *(const bf16x8*)&Kl[nt * 16 + l15][32 + grp * 8];
            f32x4 t = (f32x4){0.f, 0.f, 0.f, 0.f};
            t = __builtin_amdgcn_mfma_f32_16x16x32_bf16(aq0, bk0, t, 0, 0, 0);
            t = __builtin_amdgcn_mfma_f32_16x16x32_bf16(aq1, bk1, t, 0, 0, 0);
            s[nt] = t;
        }
        // scale + causal mask (diagonal tile only; wave-uniform branch)
        if (kt == qt) {
            for (int nt = 0; nt < 4; nt++)
                for (int r = 0; r < 4; r++) {
                    int key = kbase + nt * 16 + l15;
                    int qrow = qbase + wave * 16 + grp * 4 + r;
                    float v = s[nt][r] * scale;
                    s[nt][r] = (key <= qrow) ? v : -1e30f;
                }
        } else {
            for (int nt = 0; nt < 4; nt++)
                for (int r = 0; r < 4; r++) s[nt][r] = s[nt][r] * scale;
        }
        // online softmax: row = grp*4+r lives across lanes l15 (16 lanes)
        float mnew[4], alpha[4];
        for (int r = 0; r < 4; r++) {
            float rm = fmaxf(fmaxf(s[0][r], s[1][r]), fmaxf(s[2][r], s[3][r]));
            for (int off = 8; off >= 1; off >>= 1)
                rm = fmaxf(rm, __shfl_xor(rm, off, 64));
            mnew[r] = fmaxf(m_i[r], rm);
            alpha[r] = __expf(m_i[r] - mnew[r]);
            m_i[r] = mnew[r];
        }
        float rs[4] = {0.f, 0.f, 0.f, 0.f};
        unsigned short pm[4][4];
        for (int nt = 0; nt < 4; nt++)
            for (int r = 0; r < 4; r++) {
                float p = __expf(s[nt][r] - mnew[r]);
                rs[r] += p;
                pm[nt][r] = f32_to_bf16(p);
            }
        for (int r = 0; r < 4; r++) {
            float t = rs[r];
            for (int off = 8; off >= 1; off >>= 1) t += __shfl_xor(t, off, 64);
            l_i[r] = l_i[r] * alpha[r] + t;
            for (int nt = 0; nt < 4; nt++) acc[nt][r] = acc[nt][r] * alpha[r];
        }
        // P (C/D layout) -> LDS -> A layout
        for (int nt = 0; nt < 4; nt++)
            for (int r = 0; r < 4; r++)
                Pl[wave][grp * 4 + r][nt * 16 + l15] = pm[nt][r];
        __syncthreads();
        bf16x8 ap0 = *(const bf16x8*)&Pl[wave][l15][grp * 8];
        bf16x8 ap1 = *(const bf16x8*)&Pl[wave][l15][32 + grp * 8];
        for (int nt = 0; nt < 4; nt++) {
            bf16x8 bv0 = *(const bf16x8*)&Vl[nt * 16 + l15][grp * 8];
            bf16x8 bv1 = *(const bf16x8*)&Vl[nt * 16 + l15][32 + grp * 8];
            acc[nt] = __builtin_amdgcn_mfma_f32_16x16x32_bf16(ap0, bv0, acc[nt], 0, 0, 0);
            acc[nt] = __builtin_amdgcn_mfma_f32_16x16x32_bf16(ap1, bv1, acc[nt], 0, 0, 0);
        }
        __syncthreads();
    }

    // epilogue: out = acc / l
    int qrow0 = qbase + wave * 16 + grp * 4;
    for (int r = 0; r < 4; r++) {
        float inv = 1.f / l_i[r];
        for (int nt = 0; nt < 4; nt++)
            out[((size_t)b * 2048 + qrow0 + r) * 64 + nt * 16 + l15] = acc[nt][r] * inv;
    }
}

extern "C" void kernel_launch(void* const* d_in, const int* in_sizes, int n_in,
                              void* d_out, int out_size, void* d_ws, size_t ws_size,
                              hipStream_t stream) {
    const float* X  = (const float*)d_in[0];
    const float* Wq = (const float*)d_in[1];
    const float* Wk = (const float*)d_in[2];
    const float* Wv = (const float*)d_in[3];
    float* out = (float*)d_out;

    unsigned short* qb = (unsigned short*)d_ws;          // [16384][64] bf16
    unsigned short* kb = qb + (size_t)M_ * 64;           // [16384][64]
    unsigned short* vb = kb + (size_t)M_ * 64;           // [16384][64]
    unsigned short* wt = vb + (size_t)M_ * 64;           // [192][1024]
    unsigned short* vt = wt + (size_t)192 * 1024;        // [8][64][2048]

    prepack_w<<<768, 256, 0, stream>>>(Wq, Wk, Wv, wt);
    qkv_kernel<<<256, 256, 0, stream>>>(X, wt, qb, kb, vb);
    vtrans_kernel<<<dim3(32, 8), 256, 0, stream>>>(vb, vt);
    attn_kernel<<<dim3(32, 8), 256, 0, stream>>>(qb, kb, vt, out);
}